// Round 13
// baseline (296.094 us; speedup 1.0000x reference)
//
#include <hip/hip_runtime.h>
#include <hip/hip_fp16.h>
#include <stdint.h>

// AdaptiveGCN: B=8, L=128, D=768.  All-f16 MFMA pipeline.
// Algebra: denom==2.0 exactly; mask==all-False; (ax+out)@gw+2gb == ((a+I)@out)@gw+2gb;
// concat-linear splits into hi = x@w1[:D], hj = x@w1[D:];
// LN fused into next layer's A: (a+I)@LN(y) = lng*((a'*rstd)@y - c) + 2*lnb.
// R13: 3 GCN layers + final LN merged into ONE kernel (256 blocks, per-batch
//     spin barriers over the 32 blocks of each batch; softmax computed once,
//     kept in LDS). 7 launches -> 4. Edge unchanged from R11 (91 us).

typedef __attribute__((ext_vector_type(8))) _Float16 half8;
typedef __attribute__((ext_vector_type(2))) _Float16 half2v;
typedef __attribute__((ext_vector_type(2))) __fp16 fp16x2;   // cvt_pkrtz ret type
typedef __attribute__((ext_vector_type(4))) float floatx4;

__device__ __forceinline__ unsigned short f2h(float f) {
    union { fp16x2 p; unsigned short s[2]; } v;
    v.p = __builtin_amdgcn_cvt_pkrtz(f, f);
    return v.s[0];
}
__device__ __forceinline__ half2v f2h2v(float a, float b) {
    union { fp16x2 p; half2v h; } v;
    v.p = __builtin_amdgcn_cvt_pkrtz(a, b);
    return v.h;
}
__device__ __forceinline__ float h2f(unsigned short u) {
    union { unsigned short u; _Float16 h; } c; c.u = u;
    return (float)c.h;
}
__device__ __forceinline__ floatx4 mfma16(half8 a, half8 b, floatx4 c) {
    return __builtin_amdgcn_mfma_f32_16x16x32_f16(a, b, c, 0, 0, 0);
}
__device__ __forceinline__ void gload16(const void* g, void* lds) {
    __builtin_amdgcn_global_load_lds(
        (const __attribute__((address_space(1))) void*)g,
        (__attribute__((address_space(3))) void*)lds, 16, 0, 0);
}
// per-batch barrier over 32 blocks. __syncthreads drains each wave's stores
// (compiler emits vmcnt(0)); t0 fences (L2 wb), announces, spins, fences (inv).
__device__ __forceinline__ void batch_barrier(int* cnt, int t) {
    __syncthreads();
    if (t == 0) {
        __threadfence();
        __hip_atomic_fetch_add(cnt, 1, __ATOMIC_RELAXED, __HIP_MEMORY_SCOPE_AGENT);
        while (__hip_atomic_load(cnt, __ATOMIC_RELAXED, __HIP_MEMORY_SCOPE_AGENT) < 32)
            __builtin_amdgcn_s_sleep(8);
        __threadfence();
    }
    __syncthreads();
}

// B-fragment pack: tile(s = k-chunk32, ntile = n-group16) = 512 shorts;
// element (n_local, k_local) at lane=(k_local>>3)*16+n_local, e=k_local&7.

// ---------------- prep: all weight conversions / packings -------------------
__global__ void prep_kernel(const float* __restrict__ x, const float* __restrict__ w1,
                            const float* __restrict__ w2, const float* __restrict__ gw,
                            unsigned short* __restrict__ w1t,
                            unsigned short* __restrict__ w2p,
                            unsigned short* __restrict__ gwp,
                            unsigned short* __restrict__ xh,
                            unsigned short* __restrict__ xpk,
                            float* __restrict__ ewg,
                            float* __restrict__ maskout) {
    const int z = blockIdx.z;
    const int tx = threadIdx.x, ty = threadIdx.y;  // 32 x 8
    const int t = ty * 32 + tx;

    if (z == 5) {  // w2 (768x384 fp32 [k][n]) -> w2p frag tiles (s*24+ntg)*512
        const int s = blockIdx.x, ntg = blockIdx.y;  // both 0..23
        const int lane = t >> 2, e0 = (t & 3) * 2;
        const int n = ntg * 16 + (lane & 15);
        const int kbase = s * 32 + (lane >> 4) * 8;
        unsigned short* dst = w2p + (s * 24 + ntg) * 512 + lane * 8 + e0;
        dst[0] = f2h(w2[(kbase + e0) * 384 + n]);
        dst[1] = f2h(w2[(kbase + e0 + 1) * 384 + n]);
        return;
    }
    if (z == 6) {  // x fp32 -> f16 row-major; zero ewg + mask
        int gid = (blockIdx.y * 24 + blockIdx.x) * 256 + t;
        for (int i = gid; i < 786432; i += 24 * 24 * 256) xh[i] = f2h(x[i]);
        if (gid < 131072) ewg[gid] = 0.f;
        if (gid < 1024) maskout[gid] = 0.f;
        return;
    }
    if (z < 2) {  // w1 halves: transpose 768x768 fp32 -> f16 [n][k]
        const float* src = w1 + z * 589824;
        unsigned short* dst = w1t + z * 589824;
        const int c0 = blockIdx.x * 32, r0 = blockIdx.y * 32;
        __shared__ float tile[32][33];
        #pragma unroll
        for (int yy = ty; yy < 32; yy += 8)
            tile[yy][tx] = src[(r0 + yy) * 768 + (c0 + tx)];
        __syncthreads();
        #pragma unroll
        for (int yy = ty; yy < 32; yy += 8)
            dst[(c0 + yy) * 768 + (r0 + tx)] = f2h(tile[tx][yy]);
        return;
    }
    // frag-pack paths: z=2..4 -> gw layer (768x768 [k][n]); z=7..14 -> x batch
    const float* src; unsigned short* dstb; long tprefix; int rows;
    if (z <= 4) {
        int li = z - 2;
        src = gw + li * 589824; dstb = gwp + (long)li * 589824;
        tprefix = 0; rows = 768;
    } else {
        int bz = z - 7;
        src = x + bz * 98304; dstb = xpk;
        tprefix = (long)bz * 4; rows = 128;
    }
    const int c0 = blockIdx.x * 32, r0 = blockIdx.y * 32;
    if (r0 >= rows) return;
    __shared__ float tile[32][33];
    #pragma unroll
    for (int yy = ty; yy < 32; yy += 8)
        tile[yy][tx] = src[(r0 + yy) * 768 + (c0 + tx)];
    __syncthreads();
    if (t < 128) {
        const int n_off = t & 31, kg = t >> 5;
        const int s = r0 >> 5;
        long tileIdx = (tprefix + s) * 48 + (c0 >> 4) + (n_off >> 4);
        unsigned short* dst = dstb + tileIdx * 512 + (kg * 16 + (n_off & 15)) * 8;
        union { uint4 u; unsigned short s[8]; } pk;
        #pragma unroll
        for (int e = 0; e < 8; ++e) pk.s[e] = f2h(tile[kg * 8 + e][n_off]);
        *(uint4*)dst = pk.u;
    }
}

// --------- 128x128-tile f16 GEMM: hi|hj = x @ [w1_top|w1_bot]^T -------------
__global__ __launch_bounds__(256) void gemm128_kernel(
    const unsigned short* __restrict__ A, const unsigned short* __restrict__ Bm,
    float* __restrict__ hi, unsigned short* __restrict__ hjh) {
    __shared__ __align__(16) unsigned short sA[128 * 32];
    __shared__ __align__(16) unsigned short sB[128 * 32];
    const int n0 = blockIdx.x * 128, m0 = blockIdx.y * 128;
    const int t = threadIdx.x, wave = t >> 6, lane = t & 63;
    const int wm = wave >> 1, wn = wave & 1, col = lane & 15, q = lane >> 4;

    floatx4 acc[4][4];
    #pragma unroll
    for (int mt = 0; mt < 4; ++mt)
        #pragma unroll
        for (int nt = 0; nt < 4; ++nt) acc[mt][nt] = (floatx4){0.f, 0.f, 0.f, 0.f};

    for (int k0 = 0; k0 < 768; k0 += 32) {
        #pragma unroll
        for (int c = 0; c < 2; ++c) {
            int cid = (wave * 2 + c) * 64 + lane;
            int rw = cid >> 2;
            int half = (cid & 3) ^ ((rw >> 1) & 3);
            gload16(A + (m0 + rw) * 768 + k0 + half * 8, (char*)sA + (wave * 2 + c) * 1024);
            gload16(Bm + (n0 + rw) * 768 + k0 + half * 8, (char*)sB + (wave * 2 + c) * 1024);
        }
        __syncthreads();
        half8 aF[4], bF[4];
        #pragma unroll
        for (int mt = 0; mt < 4; ++mt) {
            int r = wm * 64 + mt * 16 + col;
            aF[mt] = *(const half8*)&sA[r * 32 + (q ^ ((r >> 1) & 3)) * 8];
        }
        #pragma unroll
        for (int nt = 0; nt < 4; ++nt) {
            int r = wn * 64 + nt * 16 + col;
            bF[nt] = *(const half8*)&sB[r * 32 + (q ^ ((r >> 1) & 3)) * 8];
        }
        #pragma unroll
        for (int mt = 0; mt < 4; ++mt)
            #pragma unroll
            for (int nt = 0; nt < 4; ++nt)
                acc[mt][nt] = mfma16(aF[mt], bF[nt], acc[mt][nt]);
        __syncthreads();
    }
    #pragma unroll
    for (int mt = 0; mt < 4; ++mt)
        #pragma unroll
        for (int nt = 0; nt < 4; ++nt) {
            int mg = m0 + wm * 64 + mt * 16 + q * 4;
            int ng = n0 + wn * 64 + nt * 16 + col;
            if (ng < 768) {
                #pragma unroll
                for (int r = 0; r < 4; ++r) hi[(mg + r) * 768 + ng] = acc[mt][nt][r];
            } else {
                #pragma unroll
                for (int r = 0; r < 4; ++r) hjh[(mg + r) * 768 + (ng - 768)] = f2h(acc[mt][nt][r]);
            }
        }
}

// ------------- edge kernel: block = (row_i, 192-col half nc) -----------------
// 256 thr = 4 waves, wave tile 2x2: wm -> 64 rows, wn -> 96 cols. acc[4][6].
// dbuf H + dbuf W, single barrier per step. ew partial -> global atomics.
__global__ __launch_bounds__(256, 3) void edge_kernel(
    const float* __restrict__ hi, const unsigned short* __restrict__ hjh,
    const float* __restrict__ b1, const unsigned short* __restrict__ w2p,
    const float* __restrict__ b2, const float* __restrict__ w3,
    float* __restrict__ ewg, float* __restrict__ statsAll) {
    __shared__ __align__(16) unsigned short sW[2][12 * 512];  // 24KB
    __shared__ __align__(16) unsigned short sH[2][128 * 32];  // 16KB
    __shared__ __align__(16) half2v sHib[384];
    __shared__ float sEw[128];

    const int t = threadIdx.x;
    const int row_i = blockIdx.x, nc = blockIdx.y;
    const int b = row_i >> 7;

    // zero 3x2048 LN stats + 24 barrier counters (6168 f32 <= 26*256)
    if (row_i < 26 && nc == 0) statsAll[row_i * 256 + t] = 0.f;

    for (int k = t; k < 384; k += 256) {
        float f0 = hi[row_i * 768 + 2 * k] + b1[2 * k];
        float f1 = hi[row_i * 768 + 2 * k + 1] + b1[2 * k + 1];
        sHib[k] = f2h2v(f0, f1);
    }
    if (t < 128) sEw[t] = 0.f;
    __syncthreads();  // sHib visible before prologue H(0) formation

    const int wave = t >> 6, lane = t & 63;
    const int col = lane & 15, q = lane >> 4;
    const int wm = wave >> 1, wn = wave & 1;
    const int hj_j = t >> 1, c0 = (t & 1) * 2, swz = (hj_j >> 1) & 3;
    const unsigned short* hjrow = hjh + (b * 128 + hj_j) * 768 + c0 * 8;
    const half2v z2 = {(_Float16)0.f, (_Float16)0.f};

    floatx4 acc[4][6];
    #pragma unroll
    for (int mt = 0; mt < 4; ++mt)
        #pragma unroll
        for (int nt = 0; nt < 6; ++nt) acc[mt][nt] = (floatx4){0.f, 0.f, 0.f, 0.f};

    // prologue: DMA W(0); form H(0); prefetch hj(1)
    #pragma unroll
    for (int c = 0; c < 3; ++c) {
        int tile = wave * 3 + c;
        gload16(w2p + (nc * 12 + tile) * 512 + lane * 8, &sW[0][tile * 512]);
    }
    uint4 g0 = *(const uint4*)(hjrow);
    uint4 g1 = *(const uint4*)(hjrow + 8);
    {
        union { uint4 u; half2v h[4]; } a0, a1;
        a0.u = g0; a1.u = g1;
        const half2v* hib = &sHib[c0 * 4];
        #pragma unroll
        for (int e = 0; e < 4; ++e) {
            a0.h[e] = __builtin_elementwise_max(a0.h[e] + hib[e], z2);
            a1.h[e] = __builtin_elementwise_max(a1.h[e] + hib[e + 4], z2);
        }
        *(uint4*)&sH[0][hj_j * 32 + ((c0 ^ swz) * 8)] = a0.u;
        *(uint4*)&sH[0][hj_j * 32 + (((c0 + 1) ^ swz) * 8)] = a1.u;
    }
    g0 = *(const uint4*)(hjrow + 32);
    g1 = *(const uint4*)(hjrow + 32 + 8);
    __syncthreads();

    for (int step = 0; step < 24; ++step) {
        const int p = step & 1;
        if (step < 23) {
            // DMA W(step+1) into other buffer
            #pragma unroll
            for (int c = 0; c < 3; ++c) {
                int tile = wave * 3 + c;
                gload16(w2p + ((step + 1) * 24 + nc * 12 + tile) * 512 + lane * 8,
                        &sW[p ^ 1][tile * 512]);
            }
            // form H(step+1) into other buffer (from regs loaded last step)
            union { uint4 u; half2v h[4]; } a0, a1;
            a0.u = g0; a1.u = g1;
            const half2v* hib = &sHib[(step + 1) * 16 + c0 * 4];
            #pragma unroll
            for (int e = 0; e < 4; ++e) {
                a0.h[e] = __builtin_elementwise_max(a0.h[e] + hib[e], z2);
                a1.h[e] = __builtin_elementwise_max(a1.h[e] + hib[e + 4], z2);
            }
            *(uint4*)&sH[p ^ 1][hj_j * 32 + ((c0 ^ swz) * 8)] = a0.u;
            *(uint4*)&sH[p ^ 1][hj_j * 32 + (((c0 + 1) ^ swz) * 8)] = a1.u;
            if (step < 22) {  // prefetch hj(step+2)
                g0 = *(const uint4*)(hjrow + (step + 2) * 32);
                g1 = *(const uint4*)(hjrow + (step + 2) * 32 + 8);
            }
        }
        // MFMA on current buffers
        half8 aF[4];
        #pragma unroll
        for (int mt = 0; mt < 4; ++mt) {
            int j = wm * 64 + mt * 16 + col;
            aF[mt] = *(const half8*)&sH[p][j * 32 + ((q ^ ((j >> 1) & 3)) * 8)];
        }
        #pragma unroll
        for (int nt = 0; nt < 6; ++nt) {
            half8 bF = *(const half8*)&sW[p][(wn * 6 + nt) * 512 + lane * 8];
            #pragma unroll
            for (int mt = 0; mt < 4; ++mt)
                acc[mt][nt] = mfma16(aF[mt], bF, acc[mt][nt]);
        }
        __syncthreads();
    }

    // epilogue: ew_partial[j] += sum_n relu(U+b2)*w3[n]  (this block's 192 cols)
    #pragma unroll
    for (int mt = 0; mt < 4; ++mt) {
        float s0 = 0.f, s1 = 0.f, s2 = 0.f, s3 = 0.f;
        #pragma unroll
        for (int nt = 0; nt < 6; ++nt) {
            int n = nc * 192 + wn * 96 + nt * 16 + col;
            float w3n = w3[n], b2n = b2[n];
            s0 += fmaxf(acc[mt][nt][0] + b2n, 0.f) * w3n;
            s1 += fmaxf(acc[mt][nt][1] + b2n, 0.f) * w3n;
            s2 += fmaxf(acc[mt][nt][2] + b2n, 0.f) * w3n;
            s3 += fmaxf(acc[mt][nt][3] + b2n, 0.f) * w3n;
        }
        #pragma unroll
        for (int off = 1; off < 16; off <<= 1) {
            s0 += __shfl_xor(s0, off); s1 += __shfl_xor(s1, off);
            s2 += __shfl_xor(s2, off); s3 += __shfl_xor(s3, off);
        }
        if (col == 0) {
            int r = wm * 64 + mt * 16 + q * 4;
            atomicAdd(&sEw[r + 0], s0); atomicAdd(&sEw[r + 1], s1);
            atomicAdd(&sEw[r + 2], s2); atomicAdd(&sEw[r + 3], s3);
        }
    }
    __syncthreads();
    if (t < 128) atomicAdd(&ewg[row_i * 128 + t], sEw[t]);
}

// ---- GCN mega-kernel: softmax once; 3 layers w/ per-batch barriers; LN out --
// grid (4 nq, 8 t, 8 b) = 256 blocks x 256 thr. Each batch's 32 blocks sync
// via device-scope arrival counters (co-residency: 256 blocks <= 256 CUs).
__global__ __launch_bounds__(256) void gcn_mega_kernel(
    const float* __restrict__ ewg, const float* __restrict__ b3,
    const float* __restrict__ adj, const unsigned short* __restrict__ xpk,
    unsigned short* __restrict__ y1T, unsigned short* __restrict__ y2T,
    float* __restrict__ stats, const float* __restrict__ lng,
    const float* __restrict__ lnb, const unsigned short* __restrict__ gwp,
    const float* __restrict__ gb, float* __restrict__ outf) {
    __shared__ __align__(16) unsigned short sBuf[16 * 776];
    __shared__ __align__(16) unsigned short sAh[16 * 128];  // block's a rows, f16
    __shared__ float sMu[128], sRstd[128];
    const int nq = blockIdx.x, t0 = blockIdx.y * 16, b = blockIdx.z;
    const int t = threadIdx.x, wave = t >> 6, lane = t & 63;
    const int col = lane & 15, q = lane >> 4;
    int* cnt = (int*)(stats + 6144);  // 24 counters, zeroed by edge

    // ---- softmax of rows t0..t0+15 (computed once, kept in LDS) ----
    {
        const float b3v = b3[0];
        #pragma unroll
        for (int r = 0; r < 4; ++r) {
            const int rowl = wave * 4 + r;
            const int rowg = b * 128 + t0 + rowl;
            const int itok = t0 + rowl;
            float p1 = ewg[rowg * 128 + lane] + b3v;
            float p2 = ewg[rowg * 128 + lane + 64] + b3v;
            float l1 = adj[rowg * 128 + lane] * (1.f / (1.f + expf(-p1)))
                       + (lane == itok ? 1.f : 0.f);
            float l2 = adj[rowg * 128 + lane + 64] * (1.f / (1.f + expf(-p2)))
                       + (lane + 64 == itok ? 1.f : 0.f);
            float m = fmaxf(l1, l2);
            #pragma unroll
            for (int off = 1; off < 64; off <<= 1) m = fmaxf(m, __shfl_xor(m, off));
            float e1 = expf(l1 - m), e2 = expf(l2 - m);
            float s = e1 + e2;
            #pragma unroll
            for (int off = 1; off < 64; off <<= 1) s += __shfl_xor(s, off);
            float inv = 1.f / s;
            sAh[rowl * 128 + lane] = f2h(e1 * inv);
            sAh[rowl * 128 + lane + 64] = f2h(e2 * inv);
        }
    }
    __syncthreads();

    for (int li = 0; li < 3; ++li) {
        const bool hasLN = (li > 0);
        const unsigned short* yprevT = (li == 1) ? y1T : y2T;
        const unsigned short* gwp_l = gwp + (long)li * 589824;
        const float* gb_l = gb + li * 768;
        const float* lng_p = hasLN ? lng + (li - 1) * 768 : nullptr;
        const float* lnb_p = hasLN ? lnb + (li - 1) * 768 : nullptr;
        float* gS_out = stats + li * 2048;
        float* gQ_out = gS_out + 1024;

        if (hasLN) {
            const float* gS_in = stats + (li - 1) * 2048;
            const float* gQ_in = gS_in + 1024;
            if (t < 128) {
                int row = b * 128 + t;
                float mu = gS_in[row] * (1.f / 768.f);
                float va = gQ_in[row] * (1.f / 768.f) - mu * mu;
                sMu[t] = mu; sRstd[t] = rsqrtf(va + 1e-5f);
            }
            __syncthreads();
        }

        // ---- phase 1 ----
        floatx4 acc1[12];
        #pragma unroll
        for (int nt = 0; nt < 12; ++nt) acc1[nt] = (floatx4){0.f, 0.f, 0.f, 0.f};
        float cp = 0.f;
        {
            const int token = t0 + col;
            #pragma unroll
            for (int kc = 0; kc < 4; ++kc) {
                half8 aF1 = *(const half8*)&sAh[col * 128 + kc * 32 + q * 8];
                const int kb = kc * 32 + q * 8;
                if (!hasLN) {
                    #pragma unroll
                    for (int e = 0; e < 8; ++e)
                        if (kb + e == token)
                            aF1[e] = (_Float16)((float)aF1[e] + 1.0f);
                    #pragma unroll
                    for (int nt = 0; nt < 12; ++nt) {
                        half8 bF = *(const half8*)&xpk[((b * 4 + kc) * 48 + wave * 12 + nt) * 512 + lane * 8];
                        acc1[nt] = mfma16(aF1, bF, acc1[nt]);
                    }
                } else {
                    #pragma unroll
                    for (int e = 0; e < 8; ++e) {
                        int tk = kb + e;
                        float av = (float)aF1[e] + (tk == token ? 1.f : 0.f);
                        float as = av * sRstd[tk];
                        cp += as * sMu[tk];
                        aF1[e] = (_Float16)as;
                    }
                    #pragma unroll
                    for (int nt = 0; nt < 12; ++nt) {
                        int n = wave * 192 + nt * 16 + col;
                        half8 bF = *(const half8*)&yprevT[(b * 768 + n) * 128 + kc * 32 + q * 8];
                        acc1[nt] = mfma16(aF1, bF, acc1[nt]);
                    }
                }
            }
        }
        float cR[4] = {0.f, 0.f, 0.f, 0.f};
        if (hasLN) {
            cp += __shfl_xor(cp, 16); cp += __shfl_xor(cp, 32);
            #pragma unroll
            for (int r = 0; r < 4; ++r) cR[r] = __shfl(cp, q * 4 + r);
        }
        // ax(_LN) -> sBuf in A-layout (row-major, stride 776)
        #pragma unroll
        for (int nt = 0; nt < 12; ++nt) {
            int n = wave * 192 + nt * 16 + col;
            float lg = hasLN ? lng_p[n] : 0.f;
            float lb = hasLN ? lnb_p[n] : 0.f;
            #pragma unroll
            for (int r = 0; r < 4; ++r) {
                float v = acc1[nt][r];
                if (hasLN) v = lg * (v - cR[r]) + 2.f * lb;
                sBuf[(q * 4 + r) * 776 + n] = f2h(v);
            }
        }
        __syncthreads();

        // ---- phase 2: Y quarter nq (explicit bF prefetch) ----
        floatx4 acc2[3];
        #pragma unroll
        for (int nt = 0; nt < 3; ++nt) acc2[nt] = (floatx4){0.f, 0.f, 0.f, 0.f};
        const int ntg0 = nq * 12 + wave * 3;
        half8 bn[3];
        #pragma unroll
        for (int nt = 0; nt < 3; ++nt)
            bn[nt] = *(const half8*)&gwp_l[(ntg0 + nt) * 512 + lane * 8];
        for (int s = 0; s < 24; ++s) {
            half8 bc[3];
            #pragma unroll
            for (int nt = 0; nt < 3; ++nt) bc[nt] = bn[nt];
            if (s < 23) {
                #pragma unroll
                for (int nt = 0; nt < 3; ++nt)
                    bn[nt] = *(const half8*)&gwp_l[((s + 1) * 48 + ntg0 + nt) * 512 + lane * 8];
            }
            half8 aF = *(const half8*)&sBuf[col * 776 + s * 32 + q * 8];
            #pragma unroll
            for (int nt = 0; nt < 3; ++nt) acc2[nt] = mfma16(aF, bc[nt], acc2[nt]);
        }

        // ---- epilogue: v = relu(Y*0.5 + gb); stats; yT store (li<2) ----
        float v[3][4];
        float ps[4] = {0.f, 0.f, 0.f, 0.f}, pq[4] = {0.f, 0.f, 0.f, 0.f};
        #pragma unroll
        for (int nt = 0; nt < 3; ++nt) {
            int n = nq * 192 + wave * 48 + nt * 16 + col;
            float g = gb_l[n];
            #pragma unroll
            for (int r = 0; r < 4; ++r) {
                v[nt][r] = fmaxf(acc2[nt][r] * 0.5f + g, 0.f);
                ps[r] += v[nt][r]; pq[r] += v[nt][r] * v[nt][r];
            }
            if (li < 2) {
                unsigned short* yT = (li == 0) ? y1T : y2T;
                union { half2v h[2]; uint2 u; } pk;
                pk.h[0] = f2h2v(v[nt][0], v[nt][1]);
                pk.h[1] = f2h2v(v[nt][2], v[nt][3]);
                *(uint2*)&yT[(b * 768 + n) * 128 + t0 + q * 4] = pk.u;
            }
        }
        #pragma unroll
        for (int off = 1; off < 16; off <<= 1) {
            #pragma unroll
            for (int r = 0; r < 4; ++r) {
                ps[r] += __shfl_xor(ps[r], off);
                pq[r] += __shfl_xor(pq[r], off);
            }
        }
        if (col == 0) {
            #pragma unroll
            for (int r = 0; r < 4; ++r) {
                int row = b * 128 + t0 + q * 4 + r;
                atomicAdd(&gS_out[row], ps[r]);
                atomicAdd(&gQ_out[row], pq[r]);
            }
        }
        batch_barrier(&cnt[li * 8 + b], t);

        if (li == 2) {  // final LN from stats3; write fp32 output
            float mu[4], rstd[4];
            #pragma unroll
            for (int r = 0; r < 4; ++r) {
                int row = b * 128 + t0 + q * 4 + r;
                float m2 = gS_out[row] * (1.f / 768.f);
                float va = gQ_out[row] * (1.f / 768.f) - m2 * m2;
                mu[r] = m2; rstd[r] = rsqrtf(va + 1e-5f);
            }
            const float* lng2 = lng + 1536;
            const float* lnb2 = lnb + 1536;
            #pragma unroll
            for (int nt = 0; nt < 3; ++nt) {
                int n = nq * 192 + wave * 48 + nt * 16 + col;
                float lg = lng2[n], lb = lnb2[n];
                #pragma unroll
                for (int r = 0; r < 4; ++r) {
                    int row = b * 128 + t0 + q * 4 + r;
                    outf[row * 768 + n] = (v[nt][r] - mu[r]) * rstd[r] * lg + lb;
                }
            }
        }
    }
}

// ------------------------------- launch -------------------------------------
extern "C" void kernel_launch(void* const* d_in, const int* in_sizes, int n_in,
                              void* d_out, int out_size, void* d_ws, size_t ws_size,
                              hipStream_t stream) {
    const float* adj = (const float*)d_in[0];
    const float* x   = (const float*)d_in[1];
    const float* w1  = (const float*)d_in[2];
    const float* b1  = (const float*)d_in[3];
    const float* w2  = (const float*)d_in[4];
    const float* b2  = (const float*)d_in[5];
    const float* w3  = (const float*)d_in[6];
    const float* b3  = (const float*)d_in[7];
    const float* gw  = (const float*)d_in[8];
    const float* gb  = (const float*)d_in[9];
    const float* lng = (const float*)d_in[10];
    const float* lnb = (const float*)d_in[11];
    float* outp = (float*)d_out;  // 786432 out + 1024 mask

    char* ws = (char*)d_ws;
    unsigned short* w1t = (unsigned short*)(ws + 0);         // 1536x768 f16 [n][k]
    unsigned short* w2p = (unsigned short*)(ws + 2359296);   // 24x24x512 frag
    unsigned short* gwp = (unsigned short*)(ws + 2949120);   // 3x(24x48x512) frag
    unsigned short* xh  = (unsigned short*)(ws + 6488064);   // 1024x768 f16
    float*          hi  = (float*)        (ws + 8060928);    // 1024x768 fp32
    unsigned short* hjh = (unsigned short*)(ws + 11206656);  // 1024x768 f16
    unsigned short* xpk = (unsigned short*)(ws + 13041664);  // 8x4x48x512 frag
    float*          ewg = (float*)        (ws + 16187392);   // 1024x128 f32
    // aliases over dead regions:
    float* stats = (float*)(ws + 6488064);                   // 3x(gS|gQ)+cnt, over xh
    unsigned short* y1T = (unsigned short*)(ws + 0);         // over w1t
    unsigned short* y2T = (unsigned short*)(ws + 8060928);   // over hi

    prep_kernel<<<dim3(24, 24, 15), dim3(32, 8), 0, stream>>>(
        x, w1, w2, gw, w1t, w2p, gwp, xh, xpk, ewg, outp + 786432);
    gemm128_kernel<<<dim3(12, 8), 256, 0, stream>>>(xh, w1t, hi, hjh);
    edge_kernel<<<dim3(1024, 2), 256, 0, stream>>>(hi, hjh, b1, w2p, b2, w3, ewg, stats);
    gcn_mega_kernel<<<dim3(4, 8, 8), 256, 0, stream>>>(
        ewg, b3, adj, xpk, y1T, y2T, stats, lng, lnb, gwp, gb, outp);
}

// Round 14
// 244.751 us; speedup vs baseline: 1.2098x; 1.2098x over previous
//
#include <hip/hip_runtime.h>
#include <hip/hip_fp16.h>
#include <stdint.h>

// AdaptiveGCN: B=8, L=128, D=768.  All-f16 MFMA pipeline.
// Algebra: denom==2.0 exactly; mask==all-False; (ax+out)@gw+2gb == ((a+I)@out)@gw+2gb;
// concat-linear splits into hi = x@w1[:D], hj = x@w1[D:];
// LN fused into next layer's A: (a+I)@LN(y) = lng*((a'*rstd)@y - c) + 2*lnb.
// R14: R11 revert (R13's fenced mega-kernel = L2-flush disaster) + 2 tail cuts:
//   (a) sm_kernel folded into edge via pairwise ticket (last nc-block of each
//       row does softmax from device-scope atomic loads; no fences, no spin);
//   (b) gemm128 writes hib=f16(hi+b1) directly (edge prologue = raw f16 copy).

typedef __attribute__((ext_vector_type(8))) _Float16 half8;
typedef __attribute__((ext_vector_type(2))) _Float16 half2v;
typedef __attribute__((ext_vector_type(2))) __fp16 fp16x2;   // cvt_pkrtz ret type
typedef __attribute__((ext_vector_type(4))) float floatx4;

__device__ __forceinline__ unsigned short f2h(float f) {
    union { fp16x2 p; unsigned short s[2]; } v;
    v.p = __builtin_amdgcn_cvt_pkrtz(f, f);
    return v.s[0];
}
__device__ __forceinline__ half2v f2h2v(float a, float b) {
    union { fp16x2 p; half2v h; } v;
    v.p = __builtin_amdgcn_cvt_pkrtz(a, b);
    return v.h;
}
__device__ __forceinline__ float h2f(unsigned short u) {
    union { unsigned short u; _Float16 h; } c; c.u = u;
    return (float)c.h;
}
__device__ __forceinline__ floatx4 mfma16(half8 a, half8 b, floatx4 c) {
    return __builtin_amdgcn_mfma_f32_16x16x32_f16(a, b, c, 0, 0, 0);
}
__device__ __forceinline__ void gload16(const void* g, void* lds) {
    __builtin_amdgcn_global_load_lds(
        (const __attribute__((address_space(1))) void*)g,
        (__attribute__((address_space(3))) void*)lds, 16, 0, 0);
}

// B-fragment pack: tile(s = k-chunk32, ntile = n-group16) = 512 shorts;
// element (n_local, k_local) at lane=(k_local>>3)*16+n_local, e=k_local&7.

// ---------------- prep: all weight conversions / packings -------------------
__global__ void prep_kernel(const float* __restrict__ x, const float* __restrict__ w1,
                            const float* __restrict__ w2, const float* __restrict__ gw,
                            unsigned short* __restrict__ w1t,
                            unsigned short* __restrict__ w2p,
                            unsigned short* __restrict__ gwp,
                            unsigned short* __restrict__ xh,
                            unsigned short* __restrict__ xpk,
                            float* __restrict__ ewg, int* __restrict__ ticket,
                            float* __restrict__ maskout) {
    const int z = blockIdx.z;
    const int tx = threadIdx.x, ty = threadIdx.y;  // 32 x 8
    const int t = ty * 32 + tx;

    if (z == 5) {  // w2 (768x384 fp32 [k][n]) -> w2p frag tiles (s*24+ntg)*512
        const int s = blockIdx.x, ntg = blockIdx.y;  // both 0..23
        const int lane = t >> 2, e0 = (t & 3) * 2;
        const int n = ntg * 16 + (lane & 15);
        const int kbase = s * 32 + (lane >> 4) * 8;
        unsigned short* dst = w2p + (s * 24 + ntg) * 512 + lane * 8 + e0;
        dst[0] = f2h(w2[(kbase + e0) * 384 + n]);
        dst[1] = f2h(w2[(kbase + e0 + 1) * 384 + n]);
        return;
    }
    if (z == 6) {  // x fp32 -> f16 row-major; zero ewg + tickets + mask
        int gid = (blockIdx.y * 24 + blockIdx.x) * 256 + t;
        for (int i = gid; i < 786432; i += 24 * 24 * 256) xh[i] = f2h(x[i]);
        if (gid < 131072) ewg[gid] = 0.f;
        if (gid < 1024) { ticket[gid] = 0; maskout[gid] = 0.f; }
        return;
    }
    if (z < 2) {  // w1 halves: transpose 768x768 fp32 -> f16 [n][k]
        const float* src = w1 + z * 589824;
        unsigned short* dst = w1t + z * 589824;
        const int c0 = blockIdx.x * 32, r0 = blockIdx.y * 32;
        __shared__ float tile[32][33];
        #pragma unroll
        for (int yy = ty; yy < 32; yy += 8)
            tile[yy][tx] = src[(r0 + yy) * 768 + (c0 + tx)];
        __syncthreads();
        #pragma unroll
        for (int yy = ty; yy < 32; yy += 8)
            dst[(c0 + yy) * 768 + (r0 + tx)] = f2h(tile[tx][yy]);
        return;
    }
    // frag-pack paths: z=2..4 -> gw layer (768x768 [k][n]); z=7..14 -> x batch
    const float* src; unsigned short* dstb; long tprefix; int rows;
    if (z <= 4) {
        int li = z - 2;
        src = gw + li * 589824; dstb = gwp + (long)li * 589824;
        tprefix = 0; rows = 768;
    } else {
        int bz = z - 7;
        src = x + bz * 98304; dstb = xpk;
        tprefix = (long)bz * 4; rows = 128;
    }
    const int c0 = blockIdx.x * 32, r0 = blockIdx.y * 32;
    if (r0 >= rows) return;
    __shared__ float tile[32][33];
    #pragma unroll
    for (int yy = ty; yy < 32; yy += 8)
        tile[yy][tx] = src[(r0 + yy) * 768 + (c0 + tx)];
    __syncthreads();
    if (t < 128) {
        const int n_off = t & 31, kg = t >> 5;
        const int s = r0 >> 5;
        long tileIdx = (tprefix + s) * 48 + (c0 >> 4) + (n_off >> 4);
        unsigned short* dst = dstb + tileIdx * 512 + (kg * 16 + (n_off & 15)) * 8;
        union { uint4 u; unsigned short s[8]; } pk;
        #pragma unroll
        for (int e = 0; e < 8; ++e) pk.s[e] = f2h(tile[kg * 8 + e][n_off]);
        *(uint4*)dst = pk.u;
    }
}

// --------- 128x128-tile f16 GEMM: hib|hj = x @ [w1_top|w1_bot]^T -------------
// n<768 -> hib = f16(acc + b1[n]); n>=768 -> hjh f16.
__global__ __launch_bounds__(256) void gemm128_kernel(
    const unsigned short* __restrict__ A, const unsigned short* __restrict__ Bm,
    const float* __restrict__ b1,
    unsigned short* __restrict__ hib, unsigned short* __restrict__ hjh) {
    __shared__ __align__(16) unsigned short sA[128 * 32];
    __shared__ __align__(16) unsigned short sB[128 * 32];
    const int n0 = blockIdx.x * 128, m0 = blockIdx.y * 128;
    const int t = threadIdx.x, wave = t >> 6, lane = t & 63;
    const int wm = wave >> 1, wn = wave & 1, col = lane & 15, q = lane >> 4;

    floatx4 acc[4][4];
    #pragma unroll
    for (int mt = 0; mt < 4; ++mt)
        #pragma unroll
        for (int nt = 0; nt < 4; ++nt) acc[mt][nt] = (floatx4){0.f, 0.f, 0.f, 0.f};

    for (int k0 = 0; k0 < 768; k0 += 32) {
        #pragma unroll
        for (int c = 0; c < 2; ++c) {
            int cid = (wave * 2 + c) * 64 + lane;
            int rw = cid >> 2;
            int half = (cid & 3) ^ ((rw >> 1) & 3);
            gload16(A + (m0 + rw) * 768 + k0 + half * 8, (char*)sA + (wave * 2 + c) * 1024);
            gload16(Bm + (n0 + rw) * 768 + k0 + half * 8, (char*)sB + (wave * 2 + c) * 1024);
        }
        __syncthreads();
        half8 aF[4], bF[4];
        #pragma unroll
        for (int mt = 0; mt < 4; ++mt) {
            int r = wm * 64 + mt * 16 + col;
            aF[mt] = *(const half8*)&sA[r * 32 + (q ^ ((r >> 1) & 3)) * 8];
        }
        #pragma unroll
        for (int nt = 0; nt < 4; ++nt) {
            int r = wn * 64 + nt * 16 + col;
            bF[nt] = *(const half8*)&sB[r * 32 + (q ^ ((r >> 1) & 3)) * 8];
        }
        #pragma unroll
        for (int mt = 0; mt < 4; ++mt)
            #pragma unroll
            for (int nt = 0; nt < 4; ++nt)
                acc[mt][nt] = mfma16(aF[mt], bF[nt], acc[mt][nt]);
        __syncthreads();
    }
    #pragma unroll
    for (int mt = 0; mt < 4; ++mt)
        #pragma unroll
        for (int nt = 0; nt < 4; ++nt) {
            int mg = m0 + wm * 64 + mt * 16 + q * 4;
            int ng = n0 + wn * 64 + nt * 16 + col;
            if (ng < 768) {
                float bb = b1[ng];
                #pragma unroll
                for (int r = 0; r < 4; ++r)
                    hib[(mg + r) * 768 + ng] = f2h(acc[mt][nt][r] + bb);
            } else {
                #pragma unroll
                for (int r = 0; r < 4; ++r) hjh[(mg + r) * 768 + (ng - 768)] = f2h(acc[mt][nt][r]);
            }
        }
}

// ------------- edge kernel: block = (row_i, 192-col half nc) -----------------
// 256 thr = 4 waves, wave tile 2x2: wm -> 64 rows, wn -> 96 cols. acc[4][6].
// dbuf H + dbuf W, single barrier per step. ew -> global atomics; the LAST of
// the 2 nc-blocks per row (ticket) computes softmax -> ah. No fences, no spin.
__global__ __launch_bounds__(256, 3) void edge_kernel(
    const unsigned short* __restrict__ hib, const unsigned short* __restrict__ hjh,
    const unsigned short* __restrict__ w2p,
    const float* __restrict__ b2, const float* __restrict__ w3,
    const float* __restrict__ b3, const float* __restrict__ adj,
    float* __restrict__ ewg, int* __restrict__ ticket,
    unsigned short* __restrict__ ah, float* __restrict__ statsAll) {
    __shared__ __align__(16) unsigned short sW[2][12 * 512];  // 24KB
    __shared__ __align__(16) unsigned short sH[2][128 * 32];  // 16KB
    __shared__ __align__(16) half2v sHib[384];
    __shared__ float sEw[128];
    __shared__ float sRed[4];
    __shared__ int sLast;

    const int t = threadIdx.x;
    const int row_i = blockIdx.x, nc = blockIdx.y;
    const int b = row_i >> 7;

    if (row_i < 24 && nc == 0) statsAll[row_i * 256 + t] = 0.f;  // zero 3x2048 LN stats

    // prologue copy: hib row (768 f16 = 384 uints)
    {
        const unsigned int* src = (const unsigned int*)(hib + row_i * 768);
        unsigned int* dst = (unsigned int*)sHib;
        for (int k = t; k < 384; k += 256) dst[k] = src[k];
    }
    if (t < 128) sEw[t] = 0.f;
    __syncthreads();  // sHib visible before prologue H(0) formation

    const int wave = t >> 6, lane = t & 63;
    const int col = lane & 15, q = lane >> 4;
    const int wm = wave >> 1, wn = wave & 1;
    const int hj_j = t >> 1, c0 = (t & 1) * 2, swz = (hj_j >> 1) & 3;
    const unsigned short* hjrow = hjh + (b * 128 + hj_j) * 768 + c0 * 8;
    const half2v z2 = {(_Float16)0.f, (_Float16)0.f};

    floatx4 acc[4][6];
    #pragma unroll
    for (int mt = 0; mt < 4; ++mt)
        #pragma unroll
        for (int nt = 0; nt < 6; ++nt) acc[mt][nt] = (floatx4){0.f, 0.f, 0.f, 0.f};

    // prologue: DMA W(0); form H(0); prefetch hj(1)
    #pragma unroll
    for (int c = 0; c < 3; ++c) {
        int tile = wave * 3 + c;
        gload16(w2p + (nc * 12 + tile) * 512 + lane * 8, &sW[0][tile * 512]);
    }
    uint4 g0 = *(const uint4*)(hjrow);
    uint4 g1 = *(const uint4*)(hjrow + 8);
    {
        union { uint4 u; half2v h[4]; } a0, a1;
        a0.u = g0; a1.u = g1;
        const half2v* hib2 = &sHib[c0 * 4];
        #pragma unroll
        for (int e = 0; e < 4; ++e) {
            a0.h[e] = __builtin_elementwise_max(a0.h[e] + hib2[e], z2);
            a1.h[e] = __builtin_elementwise_max(a1.h[e] + hib2[e + 4], z2);
        }
        *(uint4*)&sH[0][hj_j * 32 + ((c0 ^ swz) * 8)] = a0.u;
        *(uint4*)&sH[0][hj_j * 32 + (((c0 + 1) ^ swz) * 8)] = a1.u;
    }
    g0 = *(const uint4*)(hjrow + 32);
    g1 = *(const uint4*)(hjrow + 32 + 8);
    __syncthreads();

    for (int step = 0; step < 24; ++step) {
        const int p = step & 1;
        if (step < 23) {
            // DMA W(step+1) into other buffer
            #pragma unroll
            for (int c = 0; c < 3; ++c) {
                int tile = wave * 3 + c;
                gload16(w2p + ((step + 1) * 24 + nc * 12 + tile) * 512 + lane * 8,
                        &sW[p ^ 1][tile * 512]);
            }
            // form H(step+1) into other buffer (from regs loaded last step)
            union { uint4 u; half2v h[4]; } a0, a1;
            a0.u = g0; a1.u = g1;
            const half2v* hib2 = &sHib[(step + 1) * 16 + c0 * 4];
            #pragma unroll
            for (int e = 0; e < 4; ++e) {
                a0.h[e] = __builtin_elementwise_max(a0.h[e] + hib2[e], z2);
                a1.h[e] = __builtin_elementwise_max(a1.h[e] + hib2[e + 4], z2);
            }
            *(uint4*)&sH[p ^ 1][hj_j * 32 + ((c0 ^ swz) * 8)] = a0.u;
            *(uint4*)&sH[p ^ 1][hj_j * 32 + (((c0 + 1) ^ swz) * 8)] = a1.u;
            if (step < 22) {  // prefetch hj(step+2)
                g0 = *(const uint4*)(hjrow + (step + 2) * 32);
                g1 = *(const uint4*)(hjrow + (step + 2) * 32 + 8);
            }
        }
        // MFMA on current buffers
        half8 aF[4];
        #pragma unroll
        for (int mt = 0; mt < 4; ++mt) {
            int j = wm * 64 + mt * 16 + col;
            aF[mt] = *(const half8*)&sH[p][j * 32 + ((q ^ ((j >> 1) & 3)) * 8)];
        }
        #pragma unroll
        for (int nt = 0; nt < 6; ++nt) {
            half8 bF = *(const half8*)&sW[p][(wn * 6 + nt) * 512 + lane * 8];
            #pragma unroll
            for (int mt = 0; mt < 4; ++mt)
                acc[mt][nt] = mfma16(aF[mt], bF, acc[mt][nt]);
        }
        __syncthreads();
    }

    // epilogue: ew_partial[j] += sum_n relu(U+b2)*w3[n]  (this block's 192 cols)
    #pragma unroll
    for (int mt = 0; mt < 4; ++mt) {
        float s0 = 0.f, s1 = 0.f, s2 = 0.f, s3 = 0.f;
        #pragma unroll
        for (int nt = 0; nt < 6; ++nt) {
            int n = nc * 192 + wn * 96 + nt * 16 + col;
            float w3n = w3[n], b2n = b2[n];
            s0 += fmaxf(acc[mt][nt][0] + b2n, 0.f) * w3n;
            s1 += fmaxf(acc[mt][nt][1] + b2n, 0.f) * w3n;
            s2 += fmaxf(acc[mt][nt][2] + b2n, 0.f) * w3n;
            s3 += fmaxf(acc[mt][nt][3] + b2n, 0.f) * w3n;
        }
        #pragma unroll
        for (int off = 1; off < 16; off <<= 1) {
            s0 += __shfl_xor(s0, off); s1 += __shfl_xor(s1, off);
            s2 += __shfl_xor(s2, off); s3 += __shfl_xor(s3, off);
        }
        if (col == 0) {
            int r = wm * 64 + mt * 16 + q * 4;
            atomicAdd(&sEw[r + 0], s0); atomicAdd(&sEw[r + 1], s1);
            atomicAdd(&sEw[r + 2], s2); atomicAdd(&sEw[r + 3], s3);
        }
    }
    __syncthreads();
    if (t < 128) atomicAdd(&ewg[row_i * 128 + t], sEw[t]);
    __syncthreads();  // drains the ewg atomics (vmcnt(0) before barrier)
    if (t == 0)
        sLast = __hip_atomic_fetch_add(&ticket[row_i], 1, __ATOMIC_RELAXED,
                                       __HIP_MEMORY_SCOPE_AGENT);
    __syncthreads();
    if (sLast == 1) {  // I'm the last nc-block of this row: softmax -> ah
        const int i = row_i & 127;
        float logit = -1e30f;
        if (t < 128) {
            float ews = __hip_atomic_load(&ewg[row_i * 128 + t], __ATOMIC_RELAXED,
                                          __HIP_MEMORY_SCOPE_AGENT);
            float p = ews + b3[0];
            float ew = 1.f / (1.f + expf(-p));
            logit = adj[row_i * 128 + t] * ew + (t == i ? 1.f : 0.f);
        }
        float mx = logit;
        #pragma unroll
        for (int off = 1; off < 64; off <<= 1) mx = fmaxf(mx, __shfl_xor(mx, off));
        if (lane == 0 && wave < 2) sRed[wave] = mx;
        __syncthreads();
        mx = fmaxf(sRed[0], sRed[1]);
        float e = (t < 128) ? expf(logit - mx) : 0.f;
        float sm = e;
        #pragma unroll
        for (int off = 1; off < 64; off <<= 1) sm += __shfl_xor(sm, off);
        if (lane == 0 && wave < 2) sRed[2 + wave] = sm;
        __syncthreads();
        float tot = sRed[2] + sRed[3];
        if (t < 128) ah[row_i * 128 + t] = f2h(e / tot);
    }
}

// ---- GCN layer: ax(_LN) = (a+I)@[LN(y_prev)|x]; Y = ax@gw; relu+stats ------
// grid (4 nq, 8 t, 8 b) x 256.  LN fused via A-scaling when gS_in != null.
__global__ __launch_bounds__(256) void gcnA_kernel(
    const unsigned short* __restrict__ ah, const unsigned short* __restrict__ xsrc,
    const unsigned short* __restrict__ yprevT,
    const float* __restrict__ gS_in, const float* __restrict__ gQ_in,
    const float* __restrict__ lng_p, const float* __restrict__ lnb_p,
    const unsigned short* __restrict__ gwp_l, const float* __restrict__ gb_l,
    unsigned short* __restrict__ yT_out, unsigned short* __restrict__ yb_out,
    float* __restrict__ gS_out, float* __restrict__ gQ_out) {
    __shared__ __align__(16) unsigned short sBuf[16 * 776];
    __shared__ float sMu[128], sRstd[128];
    const int nq = blockIdx.x, t0 = blockIdx.y * 16, b = blockIdx.z;
    const int t = threadIdx.x, wave = t >> 6, lane = t & 63;
    const int col = lane & 15, q = lane >> 4;
    const bool hasLN = (gS_in != nullptr);

    if (hasLN) {
        if (t < 128) {
            int row = b * 128 + t;
            float mu = gS_in[row] * (1.f / 768.f);
            float va = gQ_in[row] * (1.f / 768.f) - mu * mu;
            sMu[t] = mu; sRstd[t] = rsqrtf(va + 1e-5f);
        }
        __syncthreads();
    }

    // ---- phase 1 ----
    floatx4 acc1[12];
    #pragma unroll
    for (int nt = 0; nt < 12; ++nt) acc1[nt] = (floatx4){0.f, 0.f, 0.f, 0.f};
    float cp = 0.f;
    {
        const unsigned short* arow = ah + (b * 128 + t0 + col) * 128;
        const int token = t0 + col;
        #pragma unroll
        for (int kc = 0; kc < 4; ++kc) {
            half8 aF1 = *(const half8*)&arow[kc * 32 + q * 8];
            const int kb = kc * 32 + q * 8;
            if (!hasLN) {
                if (token >= kb && token < kb + 8)
                    aF1[token - kb] = (_Float16)((float)aF1[token - kb] + 1.0f);
                #pragma unroll
                for (int nt = 0; nt < 12; ++nt) {
                    half8 bF = *(const half8*)&xsrc[((b * 4 + kc) * 48 + wave * 12 + nt) * 512 + lane * 8];
                    acc1[nt] = mfma16(aF1, bF, acc1[nt]);
                }
            } else {
                #pragma unroll
                for (int e = 0; e < 8; ++e) {
                    int tk = kb + e;
                    float av = (float)aF1[e] + (tk == token ? 1.f : 0.f);
                    float as = av * sRstd[tk];
                    cp += as * sMu[tk];
                    aF1[e] = (_Float16)as;
                }
                #pragma unroll
                for (int nt = 0; nt < 12; ++nt) {
                    int n = wave * 192 + nt * 16 + col;
                    half8 bF = *(const half8*)&yprevT[(b * 768 + n) * 128 + kc * 32 + q * 8];
                    acc1[nt] = mfma16(aF1, bF, acc1[nt]);
                }
            }
        }
    }
    float cR[4] = {0.f, 0.f, 0.f, 0.f};
    if (hasLN) {
        cp += __shfl_xor(cp, 16); cp += __shfl_xor(cp, 32);
        #pragma unroll
        for (int r = 0; r < 4; ++r) cR[r] = __shfl(cp, q * 4 + r);
    }
    // ax(_LN) -> sBuf in A-layout (row-major, stride 776)
    #pragma unroll
    for (int nt = 0; nt < 12; ++nt) {
        int n = wave * 192 + nt * 16 + col;
        float lg = hasLN ? lng_p[n] : 0.f;
        float lb = hasLN ? lnb_p[n] : 0.f;
        #pragma unroll
        for (int r = 0; r < 4; ++r) {
            float v = acc1[nt][r];
            if (hasLN) v = lg * (v - cR[r]) + 2.f * lb;
            sBuf[(q * 4 + r) * 776 + n] = f2h(v);
        }
    }
    __syncthreads();

    // ---- phase 2: Y quarter nq (explicit bF prefetch) ----
    floatx4 acc2[3];
    #pragma unroll
    for (int nt = 0; nt < 3; ++nt) acc2[nt] = (floatx4){0.f, 0.f, 0.f, 0.f};
    const int ntg0 = nq * 12 + wave * 3;
    half8 bn[3];
    #pragma unroll
    for (int nt = 0; nt < 3; ++nt)
        bn[nt] = *(const half8*)&gwp_l[(ntg0 + nt) * 512 + lane * 8];
    for (int s = 0; s < 24; ++s) {
        half8 bc[3];
        #pragma unroll
        for (int nt = 0; nt < 3; ++nt) bc[nt] = bn[nt];
        if (s < 23) {
            #pragma unroll
            for (int nt = 0; nt < 3; ++nt)
                bn[nt] = *(const half8*)&gwp_l[((s + 1) * 48 + ntg0 + nt) * 512 + lane * 8];
        }
        half8 aF = *(const half8*)&sBuf[col * 776 + s * 32 + q * 8];
        #pragma unroll
        for (int nt = 0; nt < 3; ++nt) acc2[nt] = mfma16(aF, bc[nt], acc2[nt]);
    }

    // epilogue: v = relu(Y*0.5 + gb); store yT (packed) or yb (row-major); stats
    float ps[4] = {0.f, 0.f, 0.f, 0.f}, pq[4] = {0.f, 0.f, 0.f, 0.f};
    #pragma unroll
    for (int nt = 0; nt < 3; ++nt) {
        int n = nq * 192 + wave * 48 + nt * 16 + col;
        float g = gb_l[n];
        float v[4];
        #pragma unroll
        for (int r = 0; r < 4; ++r) {
            v[r] = fmaxf(acc2[nt][r] * 0.5f + g, 0.f);
            ps[r] += v[r]; pq[r] += v[r] * v[r];
        }
        if (yT_out) {
            union { half2v h[2]; uint2 u; } pk;
            pk.h[0] = f2h2v(v[0], v[1]);
            pk.h[1] = f2h2v(v[2], v[3]);
            *(uint2*)&yT_out[(b * 768 + n) * 128 + t0 + q * 4] = pk.u;
        } else {
            #pragma unroll
            for (int r = 0; r < 4; ++r)
                yb_out[(b * 128 + t0 + q * 4 + r) * 768 + n] = f2h(v[r]);
        }
    }
    #pragma unroll
    for (int off = 1; off < 16; off <<= 1) {
        #pragma unroll
        for (int r = 0; r < 4; ++r) {
            ps[r] += __shfl_xor(ps[r], off);
            pq[r] += __shfl_xor(pq[r], off);
        }
    }
    if (col == 0) {
        #pragma unroll
        for (int r = 0; r < 4; ++r) {
            int row = b * 128 + t0 + q * 4 + r;
            atomicAdd(&gS_out[row], ps[r]);
            atomicAdd(&gQ_out[row], pq[r]);
        }
    }
}

// ---- final LN: normalize y3 and write fp32 output --------------------------
__global__ __launch_bounds__(128) void gcnBfin_kernel(
    const unsigned short* __restrict__ yb, const float* __restrict__ gS,
    const float* __restrict__ gQ, const float* __restrict__ lng_l,
    const float* __restrict__ lnb_l, float* __restrict__ outf) {
    const int row = blockIdx.x, t = threadIdx.x;
    const float mu = gS[row] * (1.f / 768.f);
    const float va = gQ[row] * (1.f / 768.f) - mu * mu;
    const float rstd = rsqrtf(va + 1e-5f);
    if (t < 96) {
        union { uint4 u; unsigned short s[8]; } v;
        v.u = *(const uint4*)&yb[row * 768 + t * 8];
        #pragma unroll
        for (int e = 0; e < 8; ++e) {
            int d = t * 8 + e;
            outf[row * 768 + d] = (h2f(v.s[e]) - mu) * rstd * lng_l[d] + lnb_l[d];
        }
    }
}

// ------------------------------- launch -------------------------------------
extern "C" void kernel_launch(void* const* d_in, const int* in_sizes, int n_in,
                              void* d_out, int out_size, void* d_ws, size_t ws_size,
                              hipStream_t stream) {
    const float* adj = (const float*)d_in[0];
    const float* x   = (const float*)d_in[1];
    const float* w1  = (const float*)d_in[2];
    const float* b1  = (const float*)d_in[3];
    const float* w2  = (const float*)d_in[4];
    const float* b2  = (const float*)d_in[5];
    const float* w3  = (const float*)d_in[6];
    const float* b3  = (const float*)d_in[7];
    const float* gw  = (const float*)d_in[8];
    const float* gb  = (const float*)d_in[9];
    const float* lng = (const float*)d_in[10];
    const float* lnb = (const float*)d_in[11];
    float* outp = (float*)d_out;  // 786432 out + 1024 mask

    char* ws = (char*)d_ws;
    unsigned short* w1t = (unsigned short*)(ws + 0);         // 1536x768 f16 [n][k]
    unsigned short* w2p = (unsigned short*)(ws + 2359296);   // 24x24x512 frag
    unsigned short* gwp = (unsigned short*)(ws + 2949120);   // 3x(24x48x512) frag
    unsigned short* xh  = (unsigned short*)(ws + 6488064);   // 1024x768 f16
    unsigned short* hib = (unsigned short*)(ws + 8060928);   // 1024x768 f16 (hi+b1)
    unsigned short* hjh = (unsigned short*)(ws + 11206656);  // 1024x768 f16
    unsigned short* ah  = (unsigned short*)(ws + 12779520);  // 8x128x128 f16
    unsigned short* xpk = (unsigned short*)(ws + 13041664);  // 8x4x48x512 frag
    unsigned short* yb  = (unsigned short*)(ws + 14614528);  // 1024x768 f16
    float*          ewg = (float*)        (ws + 16187392);   // 1024x128 f32
    int*         ticket = (int*)          (ws + 16711680);   // 1024 ints
    // aliases over dead regions:
    float* stats = (float*)(ws + 6488064);                   // 3x(gS|gQ), over xh
    unsigned short* y1T = (unsigned short*)(ws + 0);         // over w1t
    unsigned short* y2T = (unsigned short*)(ws + 8060928);   // over hib (dead post-edge)

    prep_kernel<<<dim3(24, 24, 15), dim3(32, 8), 0, stream>>>(
        x, w1, w2, gw, w1t, w2p, gwp, xh, xpk, ewg, ticket, outp + 786432);
    gemm128_kernel<<<dim3(12, 8), 256, 0, stream>>>(xh, w1t, b1, hib, hjh);
    edge_kernel<<<dim3(1024, 2), 256, 0, stream>>>(hib, hjh, w2p, b2, w3, b3, adj,
                                                   ewg, ticket, ah, stats);

    float* S1 = stats,        *Q1 = stats + 1024;
    float* S2 = stats + 2048, *Q2 = stats + 3072;
    float* S3 = stats + 4096, *Q3 = stats + 5120;

    // layer 1: src = x (packed), no LN; out y1T + stats1
    gcnA_kernel<<<dim3(4, 8, 8), 256, 0, stream>>>(
        ah, xpk, nullptr, nullptr, nullptr, nullptr, nullptr,
        gwp, gb, y1T, nullptr, S1, Q1);
    // layer 2: src = LN(y1) fused; out y2T + stats2
    gcnA_kernel<<<dim3(4, 8, 8), 256, 0, stream>>>(
        ah, nullptr, y1T, S1, Q1, lng, lnb,
        gwp + 589824, gb + 768, y2T, nullptr, S2, Q2);
    // layer 3: src = LN(y2) fused; out yb row-major + stats3
    gcnA_kernel<<<dim3(4, 8, 8), 256, 0, stream>>>(
        ah, nullptr, y2T, S2, Q2, lng + 768, lnb + 768,
        gwp + 1179648, gb + 1536, nullptr, yb, S3, Q3);
    // final LN -> fp32 output
    gcnBfin_kernel<<<1024, 128, 0, stream>>>(yb, S3, Q3, lng + 1536, lnb + 1536, outp);
}